// Round 8
// baseline (803.168 us; speedup 1.0000x reference)
//
#include <hip/hip_runtime.h>
#include <hip/hip_bf16.h>

// Problem constants
static constexpr int B_  = 16384;
static constexpr int D_  = 2048;
static constexpr int S_  = 512;
static constexpr int E_  = 8;
static constexpr int H1_ = 1024;
static constexpr int H2_ = 512;
static constexpr float EPS_ = 1e-5f;

typedef __bf16 bf16x8 __attribute__((ext_vector_type(8)));
typedef float  f32x4  __attribute__((ext_vector_type(4)));

static __device__ __forceinline__ unsigned short f2bf(float f) {
    unsigned u = __float_as_uint(f);
    unsigned r = (u + 0x7fffu + ((u >> 16) & 1u)) >> 16;   // RTNE
    return (unsigned short)r;
}

// ---------------- prepass kernels (verified R1/R2) ----------------

__global__ void cvt_bf16_kernel(const float* __restrict__ in, ushort* __restrict__ out, long n) {
    long i = ((long)blockIdx.x * blockDim.x + threadIdx.x) * 4;
    long stride = (long)gridDim.x * blockDim.x * 4;
    for (; i < n; i += stride) {
        float4 v = *(const float4*)(in + i);
        ushort4 o;
        o.x = f2bf(v.x); o.y = f2bf(v.y); o.z = f2bf(v.z); o.w = f2bf(v.w);
        *(ushort4*)(out + i) = o;
    }
}

// in: [E][R][C] f32  ->  out: [E][C][R] bf16
__global__ void transpose_cvt_kernel(const float* __restrict__ in, ushort* __restrict__ out,
                                     int R, int C) {
    __shared__ float t[64][65];
    int nbr = R >> 6, nbc = C >> 6;
    int bid = blockIdx.x;
    int e = bid / (nbr * nbc);
    int rem = bid % (nbr * nbc);
    int br = (rem / nbc) << 6, bc = (rem % nbc) << 6;
    const float* ip = in + (size_t)e * R * C;
    ushort* op = out + (size_t)e * R * C;
    int tcol = (threadIdx.x & 15) * 4;
    int trow = threadIdx.x >> 4;
#pragma unroll
    for (int p = 0; p < 4; p++) {
        int r = trow + p * 16;
        float4 v = *(const float4*)(ip + (size_t)(br + r) * C + bc + tcol);
        t[r][tcol + 0] = v.x; t[r][tcol + 1] = v.y; t[r][tcol + 2] = v.z; t[r][tcol + 3] = v.w;
    }
    __syncthreads();
#pragma unroll
    for (int p = 0; p < 4; p++) {
        int c = trow + p * 16;
        ushort4 o;
        o.x = f2bf(t[tcol + 0][c]);
        o.y = f2bf(t[tcol + 1][c]);
        o.z = f2bf(t[tcol + 2][c]);
        o.w = f2bf(t[tcol + 3][c]);
        *(ushort4*)(op + (size_t)(bc + c) * R + br + tcol) = o;
    }
}

__global__ void fold_bn_kernel(const float* __restrict__ gamma, const float* __restrict__ beta,
                               const float* __restrict__ mean, const float* __restrict__ var,
                               const float* __restrict__ bias,
                               float* __restrict__ Sv, float* __restrict__ Tv, int n) {
    int i = blockIdx.x * 256 + threadIdx.x;
    if (i < n) {
        float s = gamma[i] * rsqrtf(var[i] + EPS_);
        Sv[i] = s;
        Tv[i] = (bias[i] - mean[i]) * s + beta[i];
    }
}

__global__ void gate_kernel(const float* __restrict__ side, const float* __restrict__ Wg,
                            const float* __restrict__ bg, float* __restrict__ gate) {
    int wid = threadIdx.x >> 6, lane = threadIdx.x & 63;
    int b = blockIdx.x * 4 + wid;
    const float* sp = side + (size_t)b * S_ + lane * 8;
    float4 v0 = *(const float4*)sp;
    float4 v1 = *(const float4*)(sp + 4);
    float sv[8] = {v0.x, v0.y, v0.z, v0.w, v1.x, v1.y, v1.z, v1.w};
    float acc[E_] = {0,0,0,0,0,0,0,0};
    const float* wrow = Wg + (size_t)(lane * 8) * E_;
#pragma unroll
    for (int j = 0; j < 8; j++) {
        float4 w0 = *(const float4*)(wrow + j * E_);
        float4 w1 = *(const float4*)(wrow + j * E_ + 4);
        acc[0] += sv[j] * w0.x; acc[1] += sv[j] * w0.y;
        acc[2] += sv[j] * w0.z; acc[3] += sv[j] * w0.w;
        acc[4] += sv[j] * w1.x; acc[5] += sv[j] * w1.y;
        acc[6] += sv[j] * w1.z; acc[7] += sv[j] * w1.w;
    }
#pragma unroll
    for (int off = 32; off; off >>= 1)
#pragma unroll
        for (int e = 0; e < E_; e++) acc[e] += __shfl_xor(acc[e], off, 64);
    float m = -1e30f;
#pragma unroll
    for (int e = 0; e < E_; e++) { acc[e] += bg[e]; m = fmaxf(m, acc[e]); }
    float s = 0.f;
#pragma unroll
    for (int e = 0; e < E_; e++) { acc[e] = __expf(acc[e] - m); s += acc[e]; }
    float inv = 1.f / s;
    if (lane < E_) gate[(size_t)b * E_ + lane] = acc[lane] * inv;
}

// ---------------- shared GEMM helpers ----------------

__device__ __forceinline__ void g2lds16(const void* g, void* l) {
    __builtin_amdgcn_global_load_lds((const __attribute__((address_space(1))) unsigned int*)g,
                                     (__attribute__((address_space(3))) unsigned int*)l,
                                     16, 0, 0);
}

#define BAR()      asm volatile("s_barrier" ::: "memory")
#define WAITVM(n)  asm volatile("s_waitcnt vmcnt(" #n ")" ::: "memory")
#define MFMA(a,b,c) __builtin_amdgcn_mfma_f32_16x16x32_bf16((a),(b),(c),0,0,0)

// ---------------- GEMM1: 256x256, 1-barrier-per-K-tile, disjoint-buffer staging ----------------
// (verified R7: 519us, MfmaUtil 48%, 0 bank conflicts)
// LDS map (128 KiB): B bufs at [0,65536), A bufs at [65536,131072).
// Swizzle: LDS[row][x] = global[row][x ^ ((row&7)<<4)].
// Reads of tile t from buffer bi ONLY; staging writes tile t+1 into bi^1 ONLY
// (disjoint -> race-free under any skew). Boundary: vmcnt(0)+s_barrier.

template<int EPI>
__global__ __launch_bounds__(512, 2)
void gemm8(const ushort* __restrict__ A, const ushort* __restrict__ Bt, long aBatch,
           const float* __restrict__ Sv, const float* __restrict__ Tv,
           ushort* __restrict__ hout, float* __restrict__ outp, const float* __restrict__ gate,
           int M, int N, int K, int tilesN, int tilesM)
{
    extern __shared__ char smem[];

    const int NT  = K >> 6;
    const int tpe = tilesM * tilesN;

    const int nwg = gridDim.x, per = nwg >> 3;
    const int b0  = blockIdx.x;
    const int bid = (b0 & 7) * per + (b0 >> 3);

    const int e   = bid / tpe;
    const int rem = bid % tpe;
    const int tm  = rem / tilesN, tn = rem % tilesN;

    const char* aBase = (const char*)(A + (size_t)e * aBatch + (size_t)tm * 256 * K);
    const char* bBase = (const char*)(Bt + (size_t)e * N * K + (size_t)tn * 256 * K);
    const size_t rowB = (size_t)K * 2;
    const size_t half2 = 64 * rowB;
    const size_t half1 = 128 * rowB;

    const int tid = threadIdx.x, w = tid >> 6, lane = tid & 63;
    const int wm = w >> 2, wn = w & 3;

    const int srow = tid >> 3;
    const int scol_sw = ((tid & 7) * 16) ^ ((srow & 7) << 4);
    const int ldsW = w * 1024;

    const int lr = lane & 15;
    const int cks0 = ((lane >> 4) * 16) ^ ((lane & 7) << 4);
    const int cks1 = (64 + (lane >> 4) * 16) ^ ((lane & 7) << 4);
    const char* rdA0 = smem + 65536 + (wm * 128 + lr) * 128 + cks0;   // A ks0
    const char* rdA1 = smem + 65536 + (wm * 128 + lr) * 128 + cks1;   // A ks1
    const char* rdB0 = smem + (wn * 64 + lr) * 128 + cks0;            // B ks0
    const char* rdB1 = smem + (wn * 64 + lr) * 128 + cks1;            // B ks1

#define STG(gp, ldsoff) do { \
        g2lds16((gp), smem + (ldsoff)); \
        g2lds16((gp) + half2, smem + (ldsoff) + 8192); } while (0)

    const char* ga = aBase + (size_t)srow * rowB + scol_sw;
    const char* gb = bBase + (size_t)srow * rowB + scol_sw;

    f32x4 acc[8][4] = {};
    bf16x8 aC[4], aN[4], bC[4], bN[4];

    // prologue: stage tile0 into buffer 0; drain; refill
    STG(ga,         65536 + 0 + 0     + ldsW);
    STG(ga + half1, 65536 + 0 + 16384 + ldsW);
    STG(gb,         0     + 0 + 0     + ldsW);
    STG(gb + half1, 0     + 0 + 16384 + ldsW);
    WAITVM(0);
    BAR();

#pragma unroll
    for (int mf = 0; mf < 4; ++mf) aC[mf] = *(const bf16x8*)(rdA0 + mf * 2048);
#pragma unroll
    for (int nf = 0; nf < 4; ++nf) bC[nf] = *(const bf16x8*)(rdB0 + nf * 2048);

    const char* spA0 = ga + 128;
    const char* spA1 = ga + half1 + 128;
    const char* spB0 = gb + 128;
    const char* spB1 = gb + half1 + 128;

#pragma unroll 2
    for (int t = 0; t < NT; ++t) {
        const int bi   = t & 1;
        const int oR   = bi * 32768;
        const int oRN  = (bi ^ 1) * 32768;
        const int oSA  = 65536 + (bi ^ 1) * 32768;
        const int oSB  = (bi ^ 1) * 32768;
        const bool more = (t < NT - 1);

        // ---- P0: prefetch A ks0 hi; stage (t+1,A); MFMA aC(ks0,lo) x bC
#pragma unroll
        for (int mf = 0; mf < 4; ++mf) aN[mf] = *(const bf16x8*)(rdA0 + oR + (4 + mf) * 2048);
        if (more) {
            STG(spA0, oSA + 0 + ldsW);
            STG(spA1, oSA + 16384 + ldsW);
        }
        __builtin_amdgcn_s_setprio(1);
#pragma unroll
        for (int mf = 0; mf < 4; ++mf)
#pragma unroll
            for (int nf = 0; nf < 4; ++nf)
                acc[mf][nf] = MFMA(aC[mf], bC[nf], acc[mf][nf]);
        __builtin_amdgcn_s_setprio(0);

        // ---- P1: prefetch A ks1 lo + B ks1; stage (t+1,B-lo); MFMA aN(ks0,hi) x bC
#pragma unroll
        for (int mf = 0; mf < 4; ++mf) aC[mf] = *(const bf16x8*)(rdA1 + oR + mf * 2048);
#pragma unroll
        for (int nf = 0; nf < 4; ++nf) bN[nf] = *(const bf16x8*)(rdB1 + oR + nf * 2048);
        if (more) STG(spB0, oSB + 0 + ldsW);
        __builtin_amdgcn_s_setprio(1);
#pragma unroll
        for (int mf = 0; mf < 4; ++mf)
#pragma unroll
            for (int nf = 0; nf < 4; ++nf)
                acc[4 + mf][nf] = MFMA(aN[mf], bC[nf], acc[4 + mf][nf]);
        __builtin_amdgcn_s_setprio(0);

        // ---- P2: prefetch A ks1 hi; stage (t+1,B-hi); MFMA aC(ks1,lo) x bN
#pragma unroll
        for (int mf = 0; mf < 4; ++mf) aN[mf] = *(const bf16x8*)(rdA1 + oR + (4 + mf) * 2048);
        if (more) STG(spB1, oSB + 16384 + ldsW);
        __builtin_amdgcn_s_setprio(1);
#pragma unroll
        for (int mf = 0; mf < 4; ++mf)
#pragma unroll
            for (int nf = 0; nf < 4; ++nf)
                acc[mf][nf] = MFMA(aC[mf], bN[nf], acc[mf][nf]);
        __builtin_amdgcn_s_setprio(0);

        // ---- P3: MFMA aN(ks1,hi) x bN
        __builtin_amdgcn_s_setprio(1);
#pragma unroll
        for (int mf = 0; mf < 4; ++mf)
#pragma unroll
            for (int nf = 0; nf < 4; ++nf)
                acc[4 + mf][nf] = MFMA(aN[mf], bN[nf], acc[4 + mf][nf]);
        __builtin_amdgcn_s_setprio(0);

        if (more) {
            WAITVM(0);
            BAR();
#pragma unroll
            for (int mf = 0; mf < 4; ++mf) aC[mf] = *(const bf16x8*)(rdA0 + oRN + mf * 2048);
#pragma unroll
            for (int nf = 0; nf < 4; ++nf) bC[nf] = *(const bf16x8*)(rdB0 + oRN + nf * 2048);
        }

        spA0 += 128; spA1 += 128; spB0 += 128; spB1 += 128;
    }

    // epilogue: C/D layout col = lane&15, row = (lane>>4)*4 + reg
    const int rbase = tm * 256 + wm * 128 + (lane >> 4) * 4;
    const int cbase = tn * 256 + wn * 64 + lr;
    if (EPI == 1) {
#pragma unroll
        for (int nf = 0; nf < 4; ++nf) {
            const int col = cbase + nf * 16;
            const float s = Sv[e * N + col];
            const float tt = Tv[e * N + col];
#pragma unroll
            for (int mf = 0; mf < 8; ++mf) {
                const int row0 = rbase + mf * 16;
                f32x4 v = acc[mf][nf];
#pragma unroll
                for (int r = 0; r < 4; ++r) {
                    float x = v[r] * s + tt;
                    x = x > 0.f ? x : 0.f;
                    hout[((size_t)e * M + row0 + r) * N + col] = f2bf(x);
                }
            }
        }
    }
#undef STG
}

// ---------------- GEMM2e: expert-loop fused output kernel ----------------
// out[b][n] = sum_e gate[b][e] * relu(bn2_e( h[e][b][:] @ W2T[e][n][:] ))
// BM=128, BN=256; grid = 256 blocks = 1/CU. Flat tau over (e,kt), NT=128.
// LDS 96 KiB: B bufs [0,65536) (2x32K), A bufs [65536,98304) (2x16K).
//
// R8: same R7-proven 1-barrier schedule. Tile t reads buffer bi only; all 6
// staging loads for t+1 (A:2 + B-lo:2 in P0, B-hi:2 in P1) write bi^1 only.
// Boundary: vmcnt(0) + s_barrier, then refill ks0 fragments from bi^1.
// Expert fold (acc -> oacc) after the boundary; wave-uniform, no skew risk.

__global__ __launch_bounds__(512, 2)
void gemm2e(const ushort* __restrict__ H, const ushort* __restrict__ W2T,
            const float* __restrict__ Sv, const float* __restrict__ Tv,
            const float* __restrict__ gate, float* __restrict__ outp)
{
    extern __shared__ char smem[];

    const int b0 = blockIdx.x;
    const int bid = (b0 & 7) * 32 + (b0 >> 3);
    const int tm = bid >> 1, tn = bid & 1;

    const size_t rowB  = (size_t)H1_ * 2;
    const size_t strAE = (size_t)B_ * H1_ * 2;
    const size_t strBE = (size_t)H2_ * H1_ * 2;
    const size_t half2 = 64 * rowB;
    const size_t halfB = 128 * rowB;

    const int tid = threadIdx.x, w = tid >> 6, lane = tid & 63;
    const int wm = w >> 2, wn = w & 3;

    const int srow = tid >> 3;
    const int scol_sw = ((tid & 7) * 16) ^ ((srow & 7) << 4);
    const int ldsW = w * 1024;

    const int lr = lane & 15;
    const int cks0 = ((lane >> 4) * 16) ^ ((lane & 7) << 4);
    const int cks1 = (64 + (lane >> 4) * 16) ^ ((lane & 7) << 4);
    const char* rdA0 = smem + 65536 + (wm * 64 + lr) * 128 + cks0;
    const char* rdA1 = smem + 65536 + (wm * 64 + lr) * 128 + cks1;
    const char* rdB0 = smem + (wn * 64 + lr) * 128 + cks0;
    const char* rdB1 = smem + (wn * 64 + lr) * 128 + cks1;

    const char* ga = (const char*)H + (size_t)tm * 128 * rowB + (size_t)srow * rowB + scol_sw;
    const char* gb = (const char*)W2T + (size_t)tn * 256 * rowB + (size_t)srow * rowB + scol_sw;

    f32x4 acc[4][4] = {};
    f32x4 oacc[4][4] = {};
    bf16x8 a0[4], a1[4], b0v[4], b1v[4];

    // prologue: stage tile0 (tau=0) into buffer 0; drain; refill
    g2lds16(ga,                 smem + 65536 + 0     + ldsW);
    g2lds16(ga + half2,         smem + 65536 + 8192  + ldsW);
    g2lds16(gb,                 smem + 0     + ldsW);
    g2lds16(gb + half2,         smem + 8192  + ldsW);
    g2lds16(gb + halfB,         smem + 16384 + ldsW);
    g2lds16(gb + halfB + half2, smem + 24576 + ldsW);
    WAITVM(0);
    BAR();

#pragma unroll
    for (int mf = 0; mf < 4; ++mf) a0[mf] = *(const bf16x8*)(rdA0 + mf * 2048);
#pragma unroll
    for (int nf = 0; nf < 4; ++nf) b0v[nf] = *(const bf16x8*)(rdB0 + nf * 2048);

    const int rbase = tm * 128 + wm * 64 + (lane >> 4) * 4;
    const int cbase = tn * 256 + wn * 64 + lr;

#pragma unroll 2
    for (int t = 0; t < 128; ++t) {
        const int bi   = t & 1;
        const int oA   = bi * 16384;
        const int oB   = bi * 32768;
        const int oAn  = (bi ^ 1) * 16384;       // next-buffer offsets
        const int oBn  = (bi ^ 1) * 32768;
        const bool more = (t < 127);

        const int t1 = t + 1;
        const char* gA1 = ga + (size_t)(t1 >> 4) * strAE + (t1 & 15) * 128;
        const char* gB1 = gb + (size_t)(t1 >> 4) * strBE + (t1 & 15) * 128;

        // ---- P0: prefetch ks1 frags; stage (t+1, A + B-lo); MFMA ks0 (16)
#pragma unroll
        for (int mf = 0; mf < 4; ++mf) a1[mf] = *(const bf16x8*)(rdA1 + oA + mf * 2048);
#pragma unroll
        for (int nf = 0; nf < 4; ++nf) b1v[nf] = *(const bf16x8*)(rdB1 + oB + nf * 2048);
        if (more) {
            g2lds16(gA1,         smem + 65536 + oAn + 0    + ldsW);
            g2lds16(gA1 + half2, smem + 65536 + oAn + 8192 + ldsW);
            g2lds16(gB1,         smem + oBn + 0    + ldsW);
            g2lds16(gB1 + half2, smem + oBn + 8192 + ldsW);
        }
        __builtin_amdgcn_s_setprio(1);
#pragma unroll
        for (int mf = 0; mf < 4; ++mf)
#pragma unroll
            for (int nf = 0; nf < 4; ++nf)
                acc[mf][nf] = MFMA(a0[mf], b0v[nf], acc[mf][nf]);
        __builtin_amdgcn_s_setprio(0);

        // ---- P1: stage (t+1, B-hi); MFMA ks1 (16)
        if (more) {
            g2lds16(gB1 + halfB,         smem + oBn + 16384 + ldsW);
            g2lds16(gB1 + halfB + half2, smem + oBn + 24576 + ldsW);
        }
        __builtin_amdgcn_s_setprio(1);
#pragma unroll
        for (int mf = 0; mf < 4; ++mf)
#pragma unroll
            for (int nf = 0; nf < 4; ++nf)
                acc[mf][nf] = MFMA(a1[mf], b1v[nf], acc[mf][nf]);
        __builtin_amdgcn_s_setprio(0);

        // ---- boundary: own loads drained, then all waves'; refill ks0 frags
        if (more) {
            WAITVM(0);
            BAR();
#pragma unroll
            for (int mf = 0; mf < 4; ++mf) a0[mf] = *(const bf16x8*)(rdA0 + oAn + mf * 2048);
#pragma unroll
            for (int nf = 0; nf < 4; ++nf) b0v[nf] = *(const bf16x8*)(rdB0 + oBn + nf * 2048);
        }

        // ---- expert boundary: fold acc into gate-weighted out accumulator
        if ((t & 15) == 15) {
            const int e = t >> 4;
            float sc[4], tc[4];
#pragma unroll
            for (int nf = 0; nf < 4; ++nf) {
                sc[nf] = Sv[e * H2_ + cbase + nf * 16];
                tc[nf] = Tv[e * H2_ + cbase + nf * 16];
            }
#pragma unroll
            for (int mf = 0; mf < 4; ++mf) {
#pragma unroll
                for (int r = 0; r < 4; ++r) {
                    const int row = rbase + mf * 16 + r;
                    const float g = gate[(size_t)row * E_ + e];
#pragma unroll
                    for (int nf = 0; nf < 4; ++nf) {
                        float x = acc[mf][nf][r] * sc[nf] + tc[nf];
                        x = x > 0.f ? x : 0.f;
                        oacc[mf][nf][r] += g * x;
                    }
                }
            }
#pragma unroll
            for (int mf = 0; mf < 4; ++mf)
#pragma unroll
                for (int nf = 0; nf < 4; ++nf)
                    acc[mf][nf] = (f32x4){0.f, 0.f, 0.f, 0.f};
        }
    }

    // final write (each element owned by exactly one block)
#pragma unroll
    for (int mf = 0; mf < 4; ++mf) {
#pragma unroll
        for (int r = 0; r < 4; ++r) {
            const int row = rbase + mf * 16 + r;
#pragma unroll
            for (int nf = 0; nf < 4; ++nf)
                outp[(size_t)row * H2_ + cbase + nf * 16] = oacc[mf][nf][r];
        }
    }
}

// ---------------- launch ----------------

extern "C" void kernel_launch(void* const* d_in, const int* in_sizes, int n_in,
                              void* d_out, int out_size, void* d_ws, size_t ws_size,
                              hipStream_t stream) {
    (void)in_sizes; (void)n_in; (void)out_size; (void)ws_size;

    const float* input    = (const float*)d_in[0];
    const float* sideinfo = (const float*)d_in[1];
    const float* W1   = (const float*)d_in[2];
    const float* b1   = (const float*)d_in[3];
    const float* g1   = (const float*)d_in[4];
    const float* be1  = (const float*)d_in[5];
    const float* m1   = (const float*)d_in[6];
    const float* v1   = (const float*)d_in[7];
    const float* W2   = (const float*)d_in[8];
    const float* b2   = (const float*)d_in[9];
    const float* g2   = (const float*)d_in[10];
    const float* be2  = (const float*)d_in[11];
    const float* m2   = (const float*)d_in[12];
    const float* v2   = (const float*)d_in[13];
    const float* Wg   = (const float*)d_in[14];
    const float* bg   = (const float*)d_in[15];

    char* w = (char*)d_ws;
    size_t off = 0;
    auto carve = [&](size_t bytes) {
        void* p = w + off;
        off += (bytes + 255) & ~(size_t)255;
        return p;
    };
    ushort* Abf  = (ushort*)carve((size_t)B_ * D_ * 2);
    ushort* W1T  = (ushort*)carve((size_t)E_ * H1_ * D_ * 2);
    ushort* W2T  = (ushort*)carve((size_t)E_ * H2_ * H1_ * 2);
    ushort* hbuf = (ushort*)carve((size_t)E_ * B_ * H1_ * 2);
    float*  S1   = (float*)carve((size_t)E_ * H1_ * 4);
    float*  T1   = (float*)carve((size_t)E_ * H1_ * 4);
    float*  S2   = (float*)carve((size_t)E_ * H2_ * 4);
    float*  T2   = (float*)carve((size_t)E_ * H2_ * 4);
    float*  gatep = (float*)carve((size_t)B_ * E_ * 4);

    float* outp = (float*)d_out;

    hipFuncSetAttribute(reinterpret_cast<const void*>(&gemm8<1>),
                        hipFuncAttributeMaxDynamicSharedMemorySize, 131072);
    hipFuncSetAttribute(reinterpret_cast<const void*>(&gemm2e),
                        hipFuncAttributeMaxDynamicSharedMemorySize, 98304);

    cvt_bf16_kernel<<<4096, 256, 0, stream>>>(input, Abf, (long)B_ * D_);
    transpose_cvt_kernel<<<E_ * (D_ / 64) * (H1_ / 64), 256, 0, stream>>>(W1, W1T, D_, H1_);
    transpose_cvt_kernel<<<E_ * (H1_ / 64) * (H2_ / 64), 256, 0, stream>>>(W2, W2T, H1_, H2_);
    fold_bn_kernel<<<(E_ * H1_ + 255) / 256, 256, 0, stream>>>(g1, be1, m1, v1, b1, S1, T1, E_ * H1_);
    fold_bn_kernel<<<(E_ * H2_ + 255) / 256, 256, 0, stream>>>(g2, be2, m2, v2, b2, S2, T2, E_ * H2_);
    gate_kernel<<<B_ / 4, 256, 0, stream>>>(sideinfo, Wg, bg, gatep);

    // GEMM1: [B,D] x [D,H1] per expert -> h bf16 [E][B][H1]
    gemm8<1><<<E_ * (B_ / 256) * (H1_ / 256), 512, 131072, stream>>>(
        Abf, W1T, 0L, S1, T1, hbuf, nullptr, nullptr, B_, H1_, D_, H1_ / 256, B_ / 256);

    // GEMM2e: expert-loop, gate-weighted, writes out exactly once (no atomics)
    gemm2e<<<(B_ / 128) * (H2_ / 256), 512, 98304, stream>>>(
        hbuf, W2T, S2, T2, gatep, outp);
}

// Round 9
// 742.766 us; speedup vs baseline: 1.0813x; 1.0813x over previous
//
#include <hip/hip_runtime.h>
#include <hip/hip_bf16.h>

// Problem constants
static constexpr int B_  = 16384;
static constexpr int D_  = 2048;
static constexpr int S_  = 512;
static constexpr int E_  = 8;
static constexpr int H1_ = 1024;
static constexpr int H2_ = 512;
static constexpr float EPS_ = 1e-5f;

typedef __bf16 bf16x8 __attribute__((ext_vector_type(8)));
typedef float  f32x4  __attribute__((ext_vector_type(4)));

static __device__ __forceinline__ unsigned short f2bf(float f) {
    unsigned u = __float_as_uint(f);
    unsigned r = (u + 0x7fffu + ((u >> 16) & 1u)) >> 16;   // RTNE
    return (unsigned short)r;
}

// ---------------- prepass kernels (verified R1/R2) ----------------

__global__ void cvt_bf16_kernel(const float* __restrict__ in, ushort* __restrict__ out, long n) {
    long i = ((long)blockIdx.x * blockDim.x + threadIdx.x) * 4;
    long stride = (long)gridDim.x * blockDim.x * 4;
    for (; i < n; i += stride) {
        float4 v = *(const float4*)(in + i);
        ushort4 o;
        o.x = f2bf(v.x); o.y = f2bf(v.y); o.z = f2bf(v.z); o.w = f2bf(v.w);
        *(ushort4*)(out + i) = o;
    }
}

// in: [E][R][C] f32  ->  out: [E][C][R] bf16
__global__ void transpose_cvt_kernel(const float* __restrict__ in, ushort* __restrict__ out,
                                     int R, int C) {
    __shared__ float t[64][65];
    int nbr = R >> 6, nbc = C >> 6;
    int bid = blockIdx.x;
    int e = bid / (nbr * nbc);
    int rem = bid % (nbr * nbc);
    int br = (rem / nbc) << 6, bc = (rem % nbc) << 6;
    const float* ip = in + (size_t)e * R * C;
    ushort* op = out + (size_t)e * R * C;
    int tcol = (threadIdx.x & 15) * 4;
    int trow = threadIdx.x >> 4;
#pragma unroll
    for (int p = 0; p < 4; p++) {
        int r = trow + p * 16;
        float4 v = *(const float4*)(ip + (size_t)(br + r) * C + bc + tcol);
        t[r][tcol + 0] = v.x; t[r][tcol + 1] = v.y; t[r][tcol + 2] = v.z; t[r][tcol + 3] = v.w;
    }
    __syncthreads();
#pragma unroll
    for (int p = 0; p < 4; p++) {
        int c = trow + p * 16;
        ushort4 o;
        o.x = f2bf(t[tcol + 0][c]);
        o.y = f2bf(t[tcol + 1][c]);
        o.z = f2bf(t[tcol + 2][c]);
        o.w = f2bf(t[tcol + 3][c]);
        *(ushort4*)(op + (size_t)(bc + c) * R + br + tcol) = o;
    }
}

__global__ void fold_bn_kernel(const float* __restrict__ gamma, const float* __restrict__ beta,
                               const float* __restrict__ mean, const float* __restrict__ var,
                               const float* __restrict__ bias,
                               float* __restrict__ Sv, float* __restrict__ Tv, int n) {
    int i = blockIdx.x * 256 + threadIdx.x;
    if (i < n) {
        float s = gamma[i] * rsqrtf(var[i] + EPS_);
        Sv[i] = s;
        Tv[i] = (bias[i] - mean[i]) * s + beta[i];
    }
}

__global__ void gate_kernel(const float* __restrict__ side, const float* __restrict__ Wg,
                            const float* __restrict__ bg, float* __restrict__ gate) {
    int wid = threadIdx.x >> 6, lane = threadIdx.x & 63;
    int b = blockIdx.x * 4 + wid;
    const float* sp = side + (size_t)b * S_ + lane * 8;
    float4 v0 = *(const float4*)sp;
    float4 v1 = *(const float4*)(sp + 4);
    float sv[8] = {v0.x, v0.y, v0.z, v0.w, v1.x, v1.y, v1.z, v1.w};
    float acc[E_] = {0,0,0,0,0,0,0,0};
    const float* wrow = Wg + (size_t)(lane * 8) * E_;
#pragma unroll
    for (int j = 0; j < 8; j++) {
        float4 w0 = *(const float4*)(wrow + j * E_);
        float4 w1 = *(const float4*)(wrow + j * E_ + 4);
        acc[0] += sv[j] * w0.x; acc[1] += sv[j] * w0.y;
        acc[2] += sv[j] * w0.z; acc[3] += sv[j] * w0.w;
        acc[4] += sv[j] * w1.x; acc[5] += sv[j] * w1.y;
        acc[6] += sv[j] * w1.z; acc[7] += sv[j] * w1.w;
    }
#pragma unroll
    for (int off = 32; off; off >>= 1)
#pragma unroll
        for (int e = 0; e < E_; e++) acc[e] += __shfl_xor(acc[e], off, 64);
    float m = -1e30f;
#pragma unroll
    for (int e = 0; e < E_; e++) { acc[e] += bg[e]; m = fmaxf(m, acc[e]); }
    float s = 0.f;
#pragma unroll
    for (int e = 0; e < E_; e++) { acc[e] = __expf(acc[e] - m); s += acc[e]; }
    float inv = 1.f / s;
    if (lane < E_) gate[(size_t)b * E_ + lane] = acc[lane] * inv;
}

// ---------------- shared GEMM helpers ----------------

__device__ __forceinline__ void g2lds16(const void* g, void* l) {
    __builtin_amdgcn_global_load_lds((const __attribute__((address_space(1))) unsigned int*)g,
                                     (__attribute__((address_space(3))) unsigned int*)l,
                                     16, 0, 0);
}

#define BAR()      asm volatile("s_barrier" ::: "memory")
#define WAITVM(n)  asm volatile("s_waitcnt vmcnt(" #n ")" ::: "memory")
#define MFMA(a,b,c) __builtin_amdgcn_mfma_f32_16x16x32_bf16((a),(b),(c),0,0,0)

// ---------------- GEMM1: 256x256, 1-barrier-per-K-tile, disjoint-buffer staging ----------------
// (verified R7/R8: 519us, MfmaUtil 48%, 0 bank conflicts) -- UNCHANGED.
// Reads tile t from buffer bi only; stages tile t+1 into bi^1 only.
// Boundary: vmcnt(0)+s_barrier. Depth-1 is OK here: 64 MFMA/tile covers HBM latency.

template<int EPI>
__global__ __launch_bounds__(512, 2)
void gemm8(const ushort* __restrict__ A, const ushort* __restrict__ Bt, long aBatch,
           const float* __restrict__ Sv, const float* __restrict__ Tv,
           ushort* __restrict__ hout, float* __restrict__ outp, const float* __restrict__ gate,
           int M, int N, int K, int tilesN, int tilesM)
{
    extern __shared__ char smem[];

    const int NT  = K >> 6;
    const int tpe = tilesM * tilesN;

    const int nwg = gridDim.x, per = nwg >> 3;
    const int b0  = blockIdx.x;
    const int bid = (b0 & 7) * per + (b0 >> 3);

    const int e   = bid / tpe;
    const int rem = bid % tpe;
    const int tm  = rem / tilesN, tn = rem % tilesN;

    const char* aBase = (const char*)(A + (size_t)e * aBatch + (size_t)tm * 256 * K);
    const char* bBase = (const char*)(Bt + (size_t)e * N * K + (size_t)tn * 256 * K);
    const size_t rowB = (size_t)K * 2;
    const size_t half2 = 64 * rowB;
    const size_t half1 = 128 * rowB;

    const int tid = threadIdx.x, w = tid >> 6, lane = tid & 63;
    const int wm = w >> 2, wn = w & 3;

    const int srow = tid >> 3;
    const int scol_sw = ((tid & 7) * 16) ^ ((srow & 7) << 4);
    const int ldsW = w * 1024;

    const int lr = lane & 15;
    const int cks0 = ((lane >> 4) * 16) ^ ((lane & 7) << 4);
    const int cks1 = (64 + (lane >> 4) * 16) ^ ((lane & 7) << 4);
    const char* rdA0 = smem + 65536 + (wm * 128 + lr) * 128 + cks0;   // A ks0
    const char* rdA1 = smem + 65536 + (wm * 128 + lr) * 128 + cks1;   // A ks1
    const char* rdB0 = smem + (wn * 64 + lr) * 128 + cks0;            // B ks0
    const char* rdB1 = smem + (wn * 64 + lr) * 128 + cks1;            // B ks1

#define STG(gp, ldsoff) do { \
        g2lds16((gp), smem + (ldsoff)); \
        g2lds16((gp) + half2, smem + (ldsoff) + 8192); } while (0)

    const char* ga = aBase + (size_t)srow * rowB + scol_sw;
    const char* gb = bBase + (size_t)srow * rowB + scol_sw;

    f32x4 acc[8][4] = {};
    bf16x8 aC[4], aN[4], bC[4], bN[4];

    // prologue: stage tile0 into buffer 0; drain; refill
    STG(ga,         65536 + 0 + 0     + ldsW);
    STG(ga + half1, 65536 + 0 + 16384 + ldsW);
    STG(gb,         0     + 0 + 0     + ldsW);
    STG(gb + half1, 0     + 0 + 16384 + ldsW);
    WAITVM(0);
    BAR();

#pragma unroll
    for (int mf = 0; mf < 4; ++mf) aC[mf] = *(const bf16x8*)(rdA0 + mf * 2048);
#pragma unroll
    for (int nf = 0; nf < 4; ++nf) bC[nf] = *(const bf16x8*)(rdB0 + nf * 2048);

    const char* spA0 = ga + 128;
    const char* spA1 = ga + half1 + 128;
    const char* spB0 = gb + 128;
    const char* spB1 = gb + half1 + 128;

#pragma unroll 2
    for (int t = 0; t < NT; ++t) {
        const int bi   = t & 1;
        const int oR   = bi * 32768;
        const int oRN  = (bi ^ 1) * 32768;
        const int oSA  = 65536 + (bi ^ 1) * 32768;
        const int oSB  = (bi ^ 1) * 32768;
        const bool more = (t < NT - 1);

        // ---- P0: prefetch A ks0 hi; stage (t+1,A); MFMA aC(ks0,lo) x bC
#pragma unroll
        for (int mf = 0; mf < 4; ++mf) aN[mf] = *(const bf16x8*)(rdA0 + oR + (4 + mf) * 2048);
        if (more) {
            STG(spA0, oSA + 0 + ldsW);
            STG(spA1, oSA + 16384 + ldsW);
        }
        __builtin_amdgcn_s_setprio(1);
#pragma unroll
        for (int mf = 0; mf < 4; ++mf)
#pragma unroll
            for (int nf = 0; nf < 4; ++nf)
                acc[mf][nf] = MFMA(aC[mf], bC[nf], acc[mf][nf]);
        __builtin_amdgcn_s_setprio(0);

        // ---- P1: prefetch A ks1 lo + B ks1; stage (t+1,B-lo); MFMA aN(ks0,hi) x bC
#pragma unroll
        for (int mf = 0; mf < 4; ++mf) aC[mf] = *(const bf16x8*)(rdA1 + oR + mf * 2048);
#pragma unroll
        for (int nf = 0; nf < 4; ++nf) bN[nf] = *(const bf16x8*)(rdB1 + oR + nf * 2048);
        if (more) STG(spB0, oSB + 0 + ldsW);
        __builtin_amdgcn_s_setprio(1);
#pragma unroll
        for (int mf = 0; mf < 4; ++mf)
#pragma unroll
            for (int nf = 0; nf < 4; ++nf)
                acc[4 + mf][nf] = MFMA(aN[mf], bC[nf], acc[4 + mf][nf]);
        __builtin_amdgcn_s_setprio(0);

        // ---- P2: prefetch A ks1 hi; stage (t+1,B-hi); MFMA aC(ks1,lo) x bN
#pragma unroll
        for (int mf = 0; mf < 4; ++mf) aN[mf] = *(const bf16x8*)(rdA1 + oR + (4 + mf) * 2048);
        if (more) STG(spB1, oSB + 16384 + ldsW);
        __builtin_amdgcn_s_setprio(1);
#pragma unroll
        for (int mf = 0; mf < 4; ++mf)
#pragma unroll
            for (int nf = 0; nf < 4; ++nf)
                acc[mf][nf] = MFMA(aC[mf], bN[nf], acc[mf][nf]);
        __builtin_amdgcn_s_setprio(0);

        // ---- P3: MFMA aN(ks1,hi) x bN
        __builtin_amdgcn_s_setprio(1);
#pragma unroll
        for (int mf = 0; mf < 4; ++mf)
#pragma unroll
            for (int nf = 0; nf < 4; ++nf)
                acc[4 + mf][nf] = MFMA(aN[mf], bN[nf], acc[4 + mf][nf]);
        __builtin_amdgcn_s_setprio(0);

        if (more) {
            WAITVM(0);
            BAR();
#pragma unroll
            for (int mf = 0; mf < 4; ++mf) aC[mf] = *(const bf16x8*)(rdA0 + oRN + mf * 2048);
#pragma unroll
            for (int nf = 0; nf < 4; ++nf) bC[nf] = *(const bf16x8*)(rdB0 + oRN + nf * 2048);
        }

        spA0 += 128; spA1 += 128; spB0 += 128; spB1 += 128;
    }

    // epilogue: C/D layout col = lane&15, row = (lane>>4)*4 + reg
    const int rbase = tm * 256 + wm * 128 + (lane >> 4) * 4;
    const int cbase = tn * 256 + wn * 64 + lr;
    if (EPI == 1) {
#pragma unroll
        for (int nf = 0; nf < 4; ++nf) {
            const int col = cbase + nf * 16;
            const float s = Sv[e * N + col];
            const float tt = Tv[e * N + col];
#pragma unroll
            for (int mf = 0; mf < 8; ++mf) {
                const int row0 = rbase + mf * 16;
                f32x4 v = acc[mf][nf];
#pragma unroll
                for (int r = 0; r < 4; ++r) {
                    float x = v[r] * s + tt;
                    x = x > 0.f ? x : 0.f;
                    hout[((size_t)e * M + row0 + r) * N + col] = f2bf(x);
                }
            }
        }
    }
#undef STG
}

// ---------------- GEMM2e: expert-loop, TRIPLE-buffered counted-vmcnt pipeline ----------------
// out[b][n] = sum_e gate[b][e] * relu(bn2_e( h[e][b][:] @ W2T[e][n][:] ))
// BM=128, BN=256; grid = 256 blocks = 1/CU. Flat tau over (e,kt), NT=128.
// LDS 144 KiB: B bufs at {0,32768,65536} (32K each); A bufs at {98304,114688,131072} (16K each).
//
// R9: tile t reads buf t%3; staging during t writes tile t+2 into buf (t+2)%3 —
// disjoint from read buf AND next-read buf -> race-free under any skew.
// Boundary: vmcnt(6) (6 in flight = t+2's; t+1's landed by in-order retirement)
// + s_barrier. 2 tiles of compute (~1300cy) cover HBM latency (~900cy); fixes
// R8's depth-1 stall (only ~650cy cover with vmcnt(0)/tile).

__global__ __launch_bounds__(512, 2)
void gemm2e(const ushort* __restrict__ H, const ushort* __restrict__ W2T,
            const float* __restrict__ Sv, const float* __restrict__ Tv,
            const float* __restrict__ gate, float* __restrict__ outp)
{
    extern __shared__ char smem[];

    const int b0 = blockIdx.x;
    const int bid = (b0 & 7) * 32 + (b0 >> 3);
    const int tm = bid >> 1, tn = bid & 1;

    const size_t rowB  = (size_t)H1_ * 2;
    const size_t strAE = (size_t)B_ * H1_ * 2;
    const size_t strBE = (size_t)H2_ * H1_ * 2;
    const size_t half2 = 64 * rowB;
    const size_t halfB = 128 * rowB;

    const int tid = threadIdx.x, w = tid >> 6, lane = tid & 63;
    const int wm = w >> 2, wn = w & 3;

    const int srow = tid >> 3;
    const int scol_sw = ((tid & 7) * 16) ^ ((srow & 7) << 4);
    const int ldsW = w * 1024;

    const int lr = lane & 15;
    const int cks0 = ((lane >> 4) * 16) ^ ((lane & 7) << 4);
    const int cks1 = (64 + (lane >> 4) * 16) ^ ((lane & 7) << 4);
    // NOTE: region base carried ONLY in the rotating buffer offsets (R3 lesson).
    const char* rdA0 = smem + (wm * 64 + lr) * 128 + cks0;
    const char* rdA1 = smem + (wm * 64 + lr) * 128 + cks1;
    const char* rdB0 = smem + (wn * 64 + lr) * 128 + cks0;
    const char* rdB1 = smem + (wn * 64 + lr) * 128 + cks1;

    const char* ga = (const char*)H + (size_t)tm * 128 * rowB + (size_t)srow * rowB + scol_sw;
    const char* gb = (const char*)W2T + (size_t)tn * 256 * rowB + (size_t)srow * rowB + scol_sw;

    // stage tile tau into A buf @aOff, B buf @bOff (6 loads: A x2, B x4)
#define STG6(gAp, gBp, aOff, bOff) do { \
        g2lds16((gAp),                 smem + (aOff) + 0     + ldsW); \
        g2lds16((gAp) + half2,         smem + (aOff) + 8192  + ldsW); \
        g2lds16((gBp),                 smem + (bOff) + 0     + ldsW); \
        g2lds16((gBp) + half2,         smem + (bOff) + 8192  + ldsW); \
        g2lds16((gBp) + halfB,         smem + (bOff) + 16384 + ldsW); \
        g2lds16((gBp) + halfB + half2, smem + (bOff) + 24576 + ldsW); } while (0)

    f32x4 acc[4][4] = {};
    f32x4 oacc[4][4] = {};
    bf16x8 a0[4], a1[4], b0v[4], b1v[4];

    // rotating buffer offsets: cur = t%3, n1 = (t+1)%3, n2 = (t+2)%3
    int aCur = 98304, aN1 = 114688, aN2 = 131072;
    int bCur = 0,     bN1 = 32768,  bN2 = 65536;

    // prologue: stage tile0 -> buf0, tile1 -> buf1; wait tile0 (6 newest = tile1)
    STG6(ga, gb, aCur, bCur);
    STG6(ga + 128, gb + 128, aN1, bN1);
    WAITVM(6);
    BAR();

#pragma unroll
    for (int mf = 0; mf < 4; ++mf) a0[mf] = *(const bf16x8*)(rdA0 + aCur + mf * 2048);
#pragma unroll
    for (int nf = 0; nf < 4; ++nf) b0v[nf] = *(const bf16x8*)(rdB0 + bCur + nf * 2048);

    const int rbase = tm * 128 + wm * 64 + (lane >> 4) * 4;
    const int cbase = tn * 256 + wn * 64 + lr;

    for (int t = 0; t < 128; ++t) {
        const int t2 = t + 2;
        const bool moreS = (t2 < 128);          // stage tile t+2
        const bool moreT = (t < 127);           // boundary needed

        const char* gA2 = ga + (size_t)(t2 >> 4) * strAE + (t2 & 15) * 128;
        const char* gB2 = gb + (size_t)(t2 >> 4) * strBE + (t2 & 15) * 128;

        // ---- P0: prefetch ks1 frags (cur); stage (t+2) -> n2; MFMA ks0 (16)
#pragma unroll
        for (int mf = 0; mf < 4; ++mf) a1[mf] = *(const bf16x8*)(rdA1 + aCur + mf * 2048);
#pragma unroll
        for (int nf = 0; nf < 4; ++nf) b1v[nf] = *(const bf16x8*)(rdB1 + bCur + nf * 2048);
        if (moreS) STG6(gA2, gB2, aN2, bN2);
        __builtin_amdgcn_s_setprio(1);
#pragma unroll
        for (int mf = 0; mf < 4; ++mf)
#pragma unroll
            for (int nf = 0; nf < 4; ++nf)
                acc[mf][nf] = MFMA(a0[mf], b0v[nf], acc[mf][nf]);
        __builtin_amdgcn_s_setprio(0);

        // ---- P1: MFMA ks1 (16)
        __builtin_amdgcn_s_setprio(1);
#pragma unroll
        for (int mf = 0; mf < 4; ++mf)
#pragma unroll
            for (int nf = 0; nf < 4; ++nf)
                acc[mf][nf] = MFMA(a1[mf], b1v[nf], acc[mf][nf]);
        __builtin_amdgcn_s_setprio(0);

        // ---- boundary: t+1's loads landed (vmcnt leaves t+2's 6), all waves synced
        if (moreT) {
            if (moreS) { WAITVM(6); } else { WAITVM(0); }
            BAR();
#pragma unroll
            for (int mf = 0; mf < 4; ++mf) a0[mf] = *(const bf16x8*)(rdA0 + aN1 + mf * 2048);
#pragma unroll
            for (int nf = 0; nf < 4; ++nf) b0v[nf] = *(const bf16x8*)(rdB0 + bN1 + nf * 2048);
        }

        // ---- expert boundary: fold acc into gate-weighted out accumulator
        if ((t & 15) == 15) {
            const int e = t >> 4;
            float sc[4], tc[4];
#pragma unroll
            for (int nf = 0; nf < 4; ++nf) {
                sc[nf] = Sv[e * H2_ + cbase + nf * 16];
                tc[nf] = Tv[e * H2_ + cbase + nf * 16];
            }
#pragma unroll
            for (int mf = 0; mf < 4; ++mf) {
#pragma unroll
                for (int r = 0; r < 4; ++r) {
                    const int row = rbase + mf * 16 + r;
                    const float g = gate[(size_t)row * E_ + e];
#pragma unroll
                    for (int nf = 0; nf < 4; ++nf) {
                        float x = acc[mf][nf][r] * sc[nf] + tc[nf];
                        x = x > 0.f ? x : 0.f;
                        oacc[mf][nf][r] += g * x;
                    }
                }
            }
#pragma unroll
            for (int mf = 0; mf < 4; ++mf)
#pragma unroll
                for (int nf = 0; nf < 4; ++nf)
                    acc[mf][nf] = (f32x4){0.f, 0.f, 0.f, 0.f};
        }

        // rotate buffers: cur <- n1 <- n2 <- cur
        const int ta = aCur; aCur = aN1; aN1 = aN2; aN2 = ta;
        const int tb = bCur; bCur = bN1; bN1 = bN2; bN2 = tb;
    }

    // final write (each element owned by exactly one block)
#pragma unroll
    for (int mf = 0; mf < 4; ++mf) {
#pragma unroll
        for (int r = 0; r < 4; ++r) {
            const int row = rbase + mf * 16 + r;
#pragma unroll
            for (int nf = 0; nf < 4; ++nf)
                outp[(size_t)row * H2_ + cbase + nf * 16] = oacc[mf][nf][r];
        }
    }
#undef STG6
}

// ---------------- launch ----------------

extern "C" void kernel_launch(void* const* d_in, const int* in_sizes, int n_in,
                              void* d_out, int out_size, void* d_ws, size_t ws_size,
                              hipStream_t stream) {
    (void)in_sizes; (void)n_in; (void)out_size; (void)ws_size;

    const float* input    = (const float*)d_in[0];
    const float* sideinfo = (const float*)d_in[1];
    const float* W1   = (const float*)d_in[2];
    const float* b1   = (const float*)d_in[3];
    const float* g1   = (const float*)d_in[4];
    const float* be1  = (const float*)d_in[5];
    const float* m1   = (const float*)d_in[6];
    const float* v1   = (const float*)d_in[7];
    const float* W2   = (const float*)d_in[8];
    const float* b2   = (const float*)d_in[9];
    const float* g2   = (const float*)d_in[10];
    const float* be2  = (const float*)d_in[11];
    const float* m2   = (const float*)d_in[12];
    const float* v2   = (const float*)d_in[13];
    const float* Wg   = (const float*)d_in[14];
    const float* bg   = (const float*)d_in[15];

    char* w = (char*)d_ws;
    size_t off = 0;
    auto carve = [&](size_t bytes) {
        void* p = w + off;
        off += (bytes + 255) & ~(size_t)255;
        return p;
    };
    ushort* Abf  = (ushort*)carve((size_t)B_ * D_ * 2);
    ushort* W1T  = (ushort*)carve((size_t)E_ * H1_ * D_ * 2);
    ushort* W2T  = (ushort*)carve((size_t)E_ * H2_ * H1_ * 2);
    ushort* hbuf = (ushort*)carve((size_t)E_ * B_ * H1_ * 2);
    float*  S1   = (float*)carve((size_t)E_ * H1_ * 4);
    float*  T1   = (float*)carve((size_t)E_ * H1_ * 4);
    float*  S2   = (float*)carve((size_t)E_ * H2_ * 4);
    float*  T2   = (float*)carve((size_t)E_ * H2_ * 4);
    float*  gatep = (float*)carve((size_t)B_ * E_ * 4);

    float* outp = (float*)d_out;

    hipFuncSetAttribute(reinterpret_cast<const void*>(&gemm8<1>),
                        hipFuncAttributeMaxDynamicSharedMemorySize, 131072);
    hipFuncSetAttribute(reinterpret_cast<const void*>(&gemm2e),
                        hipFuncAttributeMaxDynamicSharedMemorySize, 147456);

    cvt_bf16_kernel<<<4096, 256, 0, stream>>>(input, Abf, (long)B_ * D_);
    transpose_cvt_kernel<<<E_ * (D_ / 64) * (H1_ / 64), 256, 0, stream>>>(W1, W1T, D_, H1_);
    transpose_cvt_kernel<<<E_ * (H1_ / 64) * (H2_ / 64), 256, 0, stream>>>(W2, W2T, H1_, H2_);
    fold_bn_kernel<<<(E_ * H1_ + 255) / 256, 256, 0, stream>>>(g1, be1, m1, v1, b1, S1, T1, E_ * H1_);
    fold_bn_kernel<<<(E_ * H2_ + 255) / 256, 256, 0, stream>>>(g2, be2, m2, v2, b2, S2, T2, E_ * H2_);
    gate_kernel<<<B_ / 4, 256, 0, stream>>>(sideinfo, Wg, bg, gatep);

    // GEMM1: [B,D] x [D,H1] per expert -> h bf16 [E][B][H1]
    gemm8<1><<<E_ * (B_ / 256) * (H1_ / 256), 512, 131072, stream>>>(
        Abf, W1T, 0L, S1, T1, hbuf, nullptr, nullptr, B_, H1_, D_, H1_ / 256, B_ / 256);

    // GEMM2e: expert-loop, gate-weighted, writes out exactly once (no atomics)
    gemm2e<<<(B_ / 128) * (H2_ / 256), 512, 147456, stream>>>(
        hbuf, W2T, S2, T2, gatep, outp);
}

// Round 10
// 702.361 us; speedup vs baseline: 1.1435x; 1.0575x over previous
//
#include <hip/hip_runtime.h>
#include <hip/hip_bf16.h>

// Problem constants
static constexpr int B_  = 16384;
static constexpr int D_  = 2048;
static constexpr int S_  = 512;
static constexpr int E_  = 8;
static constexpr int H1_ = 1024;
static constexpr int H2_ = 512;
static constexpr float EPS_ = 1e-5f;

typedef __bf16 bf16x8 __attribute__((ext_vector_type(8)));
typedef float  f32x4  __attribute__((ext_vector_type(4)));

static __device__ __forceinline__ unsigned short f2bf(float f) {
    unsigned u = __float_as_uint(f);
    unsigned r = (u + 0x7fffu + ((u >> 16) & 1u)) >> 16;   // RTNE
    return (unsigned short)r;
}

// ---------------- prepass kernels (verified R1/R2) ----------------

__global__ void cvt_bf16_kernel(const float* __restrict__ in, ushort* __restrict__ out, long n) {
    long i = ((long)blockIdx.x * blockDim.x + threadIdx.x) * 4;
    long stride = (long)gridDim.x * blockDim.x * 4;
    for (; i < n; i += stride) {
        float4 v = *(const float4*)(in + i);
        ushort4 o;
        o.x = f2bf(v.x); o.y = f2bf(v.y); o.z = f2bf(v.z); o.w = f2bf(v.w);
        *(ushort4*)(out + i) = o;
    }
}

// in: [E][R][C] f32  ->  out: [E][C][R] bf16
__global__ void transpose_cvt_kernel(const float* __restrict__ in, ushort* __restrict__ out,
                                     int R, int C) {
    __shared__ float t[64][65];
    int nbr = R >> 6, nbc = C >> 6;
    int bid = blockIdx.x;
    int e = bid / (nbr * nbc);
    int rem = bid % (nbr * nbc);
    int br = (rem / nbc) << 6, bc = (rem % nbc) << 6;
    const float* ip = in + (size_t)e * R * C;
    ushort* op = out + (size_t)e * R * C;
    int tcol = (threadIdx.x & 15) * 4;
    int trow = threadIdx.x >> 4;
#pragma unroll
    for (int p = 0; p < 4; p++) {
        int r = trow + p * 16;
        float4 v = *(const float4*)(ip + (size_t)(br + r) * C + bc + tcol);
        t[r][tcol + 0] = v.x; t[r][tcol + 1] = v.y; t[r][tcol + 2] = v.z; t[r][tcol + 3] = v.w;
    }
    __syncthreads();
#pragma unroll
    for (int p = 0; p < 4; p++) {
        int c = trow + p * 16;
        ushort4 o;
        o.x = f2bf(t[tcol + 0][c]);
        o.y = f2bf(t[tcol + 1][c]);
        o.z = f2bf(t[tcol + 2][c]);
        o.w = f2bf(t[tcol + 3][c]);
        *(ushort4*)(op + (size_t)(bc + c) * R + br + tcol) = o;
    }
}

__global__ void fold_bn_kernel(const float* __restrict__ gamma, const float* __restrict__ beta,
                               const float* __restrict__ mean, const float* __restrict__ var,
                               const float* __restrict__ bias,
                               float* __restrict__ Sv, float* __restrict__ Tv, int n) {
    int i = blockIdx.x * 256 + threadIdx.x;
    if (i < n) {
        float s = gamma[i] * rsqrtf(var[i] + EPS_);
        Sv[i] = s;
        Tv[i] = (bias[i] - mean[i]) * s + beta[i];
    }
}

__global__ void gate_kernel(const float* __restrict__ side, const float* __restrict__ Wg,
                            const float* __restrict__ bg, float* __restrict__ gate) {
    int wid = threadIdx.x >> 6, lane = threadIdx.x & 63;
    int b = blockIdx.x * 4 + wid;
    const float* sp = side + (size_t)b * S_ + lane * 8;
    float4 v0 = *(const float4*)sp;
    float4 v1 = *(const float4*)(sp + 4);
    float sv[8] = {v0.x, v0.y, v0.z, v0.w, v1.x, v1.y, v1.z, v1.w};
    float acc[E_] = {0,0,0,0,0,0,0,0};
    const float* wrow = Wg + (size_t)(lane * 8) * E_;
#pragma unroll
    for (int j = 0; j < 8; j++) {
        float4 w0 = *(const float4*)(wrow + j * E_);
        float4 w1 = *(const float4*)(wrow + j * E_ + 4);
        acc[0] += sv[j] * w0.x; acc[1] += sv[j] * w0.y;
        acc[2] += sv[j] * w0.z; acc[3] += sv[j] * w0.w;
        acc[4] += sv[j] * w1.x; acc[5] += sv[j] * w1.y;
        acc[6] += sv[j] * w1.z; acc[7] += sv[j] * w1.w;
    }
#pragma unroll
    for (int off = 32; off; off >>= 1)
#pragma unroll
        for (int e = 0; e < E_; e++) acc[e] += __shfl_xor(acc[e], off, 64);
    float m = -1e30f;
#pragma unroll
    for (int e = 0; e < E_; e++) { acc[e] += bg[e]; m = fmaxf(m, acc[e]); }
    float s = 0.f;
#pragma unroll
    for (int e = 0; e < E_; e++) { acc[e] = __expf(acc[e] - m); s += acc[e]; }
    float inv = 1.f / s;
    if (lane < E_) gate[(size_t)b * E_ + lane] = acc[lane] * inv;
}

// ---------------- shared GEMM helpers ----------------

__device__ __forceinline__ void g2lds16(const void* g, void* l) {
    __builtin_amdgcn_global_load_lds((const __attribute__((address_space(1))) unsigned int*)g,
                                     (__attribute__((address_space(3))) unsigned int*)l,
                                     16, 0, 0);
}

#define BAR()      asm volatile("s_barrier" ::: "memory")
#define WAITVM(n)  asm volatile("s_waitcnt vmcnt(" #n ")" ::: "memory")
#define MFMA(a,b,c) __builtin_amdgcn_mfma_f32_16x16x32_bf16((a),(b),(c),0,0,0)

// ---------------- GEMM1: 256x256, counted-vmcnt (T4) asymmetric pipeline ----------------
// LDS map (160 KiB): B bufs at {0,32768,65536} (triple, rotating);
//                    A bufs at {98304,131072} (double, bi = t&1).
// Swizzle: LDS[row][x] = global[row][x ^ ((row&7)<<4)] (both-sides, rule #21).
//
// R10 (T4): tile t reads A from buf bi, B from buf bCur (=t%3).
//   P0 stages A(t+1) -> buf bi^1   (disjoint from read buf; R7-proven)
//   P1/P2 stage B(t+2) -> buf bN2  (disjoint from bCur AND bN1 -> race-free any skew)
// Boundary: vmcnt(4) — A(t+1)'s 4 loads (older) retired, B(t+2)'s 4 stay in
// flight across the barrier (counted vmcnt, never 0 in steady state — the
// m218 lever). vmcnt(0) only at t==NT-2. 1 barrier/tile.

template<int EPI>
__global__ __launch_bounds__(512, 2)
void gemm8(const ushort* __restrict__ A, const ushort* __restrict__ Bt, long aBatch,
           const float* __restrict__ Sv, const float* __restrict__ Tv,
           ushort* __restrict__ hout, float* __restrict__ outp, const float* __restrict__ gate,
           int M, int N, int K, int tilesN, int tilesM)
{
    extern __shared__ char smem[];

    const int NT  = K >> 6;
    const int tpe = tilesM * tilesN;

    const int nwg = gridDim.x, per = nwg >> 3;
    const int b0  = blockIdx.x;
    const int bid = (b0 & 7) * per + (b0 >> 3);

    const int e   = bid / tpe;
    const int rem = bid % tpe;
    const int tm  = rem / tilesN, tn = rem % tilesN;

    const char* aBase = (const char*)(A + (size_t)e * aBatch + (size_t)tm * 256 * K);
    const char* bBase = (const char*)(Bt + (size_t)e * N * K + (size_t)tn * 256 * K);
    const size_t rowB = (size_t)K * 2;
    const size_t half2 = 64 * rowB;
    const size_t half1 = 128 * rowB;

    const int tid = threadIdx.x, w = tid >> 6, lane = tid & 63;
    const int wm = w >> 2, wn = w & 3;

    const int srow = tid >> 3;
    const int scol_sw = ((tid & 7) * 16) ^ ((srow & 7) << 4);
    const int ldsW = w * 1024;

    const int lr = lane & 15;
    const int cks0 = ((lane >> 4) * 16) ^ ((lane & 7) << 4);
    const int cks1 = (64 + (lane >> 4) * 16) ^ ((lane & 7) << 4);
    // A region base (98304) baked into rdA*; per-tile offset = bi*32768 ONLY (R3 lesson).
    const char* rdA0 = smem + 98304 + (wm * 128 + lr) * 128 + cks0;   // A ks0
    const char* rdA1 = smem + 98304 + (wm * 128 + lr) * 128 + cks1;   // A ks1
    // B region base 0; per-tile offset = rotating bCur in {0,32768,65536}.
    const char* rdB0 = smem + (wn * 64 + lr) * 128 + cks0;            // B ks0
    const char* rdB1 = smem + (wn * 64 + lr) * 128 + cks1;            // B ks1

#define STG(gp, ldsoff) do { \
        g2lds16((gp), smem + (ldsoff)); \
        g2lds16((gp) + half2, smem + (ldsoff) + 8192); } while (0)

    const char* ga = aBase + (size_t)srow * rowB + scol_sw;
    const char* gb = bBase + (size_t)srow * rowB + scol_sw;

    f32x4 acc[8][4] = {};
    bf16x8 aC[4], aN[4], bC[4], bN[4];

    // rotating B buffer offsets: bCur = t%3, bN1 = (t+1)%3, bN2 = (t+2)%3
    int bCur = 0, bN1 = 32768, bN2 = 65536;

    // prologue: A(0)->A0, B(0)->B0, B(1)->B1; wait A(0),B(0) (4 newest = B(1))
    STG(ga,                98304 + 0 + 0     + ldsW);
    STG(ga + half1,        98304 + 0 + 16384 + ldsW);
    STG(gb,                0     + 0     + ldsW);
    STG(gb + half1,        0     + 16384 + ldsW);
    STG(gb + 128,          32768 + 0     + ldsW);
    STG(gb + half1 + 128,  32768 + 16384 + ldsW);
    WAITVM(4);
    BAR();

#pragma unroll
    for (int mf = 0; mf < 4; ++mf) aC[mf] = *(const bf16x8*)(rdA0 + mf * 2048);
#pragma unroll
    for (int nf = 0; nf < 4; ++nf) bC[nf] = *(const bf16x8*)(rdB0 + nf * 2048);

    // staging pointers: A -> tile t+1; B -> tile t+2 (advance 128 B/tile)
    const char* spA0 = ga + 128;
    const char* spA1 = ga + half1 + 128;
    const char* spB0 = gb + 256;
    const char* spB1 = gb + half1 + 256;

#pragma unroll 2
    for (int t = 0; t < NT; ++t) {
        const int bi    = t & 1;
        const int oRA   = bi * 32768;              // A read offset
        const int oRAN  = (bi ^ 1) * 32768;        // next-tile A read offset
        const int oSA   = 98304 + (bi ^ 1) * 32768; // A stage base (region + buf)
        const bool moreA = (t < NT - 1);
        const bool moreB = (t < NT - 2);

        // ---- P0: prefetch A ks0 hi; stage A(t+1) (4 loads, FIRST); MFMA aC(ks0,lo) x bC
#pragma unroll
        for (int mf = 0; mf < 4; ++mf) aN[mf] = *(const bf16x8*)(rdA0 + oRA + (4 + mf) * 2048);
        if (moreA) {
            STG(spA0, oSA + 0 + ldsW);
            STG(spA1, oSA + 16384 + ldsW);
        }
        __builtin_amdgcn_s_setprio(1);
#pragma unroll
        for (int mf = 0; mf < 4; ++mf)
#pragma unroll
            for (int nf = 0; nf < 4; ++nf)
                acc[mf][nf] = MFMA(aC[mf], bC[nf], acc[mf][nf]);
        __builtin_amdgcn_s_setprio(0);

        // ---- P1: prefetch A ks1 lo + B ks1; stage B(t+2) lo; MFMA aN(ks0,hi) x bC
#pragma unroll
        for (int mf = 0; mf < 4; ++mf) aC[mf] = *(const bf16x8*)(rdA1 + oRA + mf * 2048);
#pragma unroll
        for (int nf = 0; nf < 4; ++nf) bN[nf] = *(const bf16x8*)(rdB1 + bCur + nf * 2048);
        if (moreB) STG(spB0, bN2 + 0 + ldsW);
        __builtin_amdgcn_s_setprio(1);
#pragma unroll
        for (int mf = 0; mf < 4; ++mf)
#pragma unroll
            for (int nf = 0; nf < 4; ++nf)
                acc[4 + mf][nf] = MFMA(aN[mf], bC[nf], acc[4 + mf][nf]);
        __builtin_amdgcn_s_setprio(0);

        // ---- P2: prefetch A ks1 hi; stage B(t+2) hi; MFMA aC(ks1,lo) x bN
#pragma unroll
        for (int mf = 0; mf < 4; ++mf) aN[mf] = *(const bf16x8*)(rdA1 + oRA + (4 + mf) * 2048);
        if (moreB) STG(spB1, bN2 + 16384 + ldsW);
        __builtin_amdgcn_s_setprio(1);
#pragma unroll
        for (int mf = 0; mf < 4; ++mf)
#pragma unroll
            for (int nf = 0; nf < 4; ++nf)
                acc[mf][nf] = MFMA(aC[mf], bN[nf], acc[mf][nf]);
        __builtin_amdgcn_s_setprio(0);

        // ---- P3: MFMA aN(ks1,hi) x bN
        __builtin_amdgcn_s_setprio(1);
#pragma unroll
        for (int mf = 0; mf < 4; ++mf)
#pragma unroll
            for (int nf = 0; nf < 4; ++nf)
                acc[4 + mf][nf] = MFMA(aN[mf], bN[nf], acc[4 + mf][nf]);
        __builtin_amdgcn_s_setprio(0);

        // ---- boundary: counted vmcnt — A(t+1) retired, B(t+2)'s 4 stay in flight
        if (moreA) {
            if (moreB) { WAITVM(4); } else { WAITVM(0); }
            BAR();
#pragma unroll
            for (int mf = 0; mf < 4; ++mf) aC[mf] = *(const bf16x8*)(rdA0 + oRAN + mf * 2048);
#pragma unroll
            for (int nf = 0; nf < 4; ++nf) bC[nf] = *(const bf16x8*)(rdB0 + bN1 + nf * 2048);
        }

        spA0 += 128; spA1 += 128; spB0 += 128; spB1 += 128;
        const int tb = bCur; bCur = bN1; bN1 = bN2; bN2 = tb;
    }

    // epilogue: C/D layout col = lane&15, row = (lane>>4)*4 + reg
    const int rbase = tm * 256 + wm * 128 + (lane >> 4) * 4;
    const int cbase = tn * 256 + wn * 64 + lr;
    if (EPI == 1) {
#pragma unroll
        for (int nf = 0; nf < 4; ++nf) {
            const int col = cbase + nf * 16;
            const float s = Sv[e * N + col];
            const float tt = Tv[e * N + col];
#pragma unroll
            for (int mf = 0; mf < 8; ++mf) {
                const int row0 = rbase + mf * 16;
                f32x4 v = acc[mf][nf];
#pragma unroll
                for (int r = 0; r < 4; ++r) {
                    float x = v[r] * s + tt;
                    x = x > 0.f ? x : 0.f;
                    hout[((size_t)e * M + row0 + r) * N + col] = f2bf(x);
                }
            }
        }
    }
#undef STG
}

// ---------------- GEMM2e: expert-loop, TRIPLE-buffered counted-vmcnt pipeline ----------------
// (verified R9) out[b][n] = sum_e gate[b][e] * relu(bn2_e( h[e][b] @ W2T[e][n] ))
// BM=128, BN=256; grid = 256 blocks = 1/CU. Flat tau over (e,kt), NT=128.
// LDS 144 KiB: B bufs {0,32768,65536}; A bufs {98304,114688,131072}.

__global__ __launch_bounds__(512, 2)
void gemm2e(const ushort* __restrict__ H, const ushort* __restrict__ W2T,
            const float* __restrict__ Sv, const float* __restrict__ Tv,
            const float* __restrict__ gate, float* __restrict__ outp)
{
    extern __shared__ char smem[];

    const int b0 = blockIdx.x;
    const int bid = (b0 & 7) * 32 + (b0 >> 3);
    const int tm = bid >> 1, tn = bid & 1;

    const size_t rowB  = (size_t)H1_ * 2;
    const size_t strAE = (size_t)B_ * H1_ * 2;
    const size_t strBE = (size_t)H2_ * H1_ * 2;
    const size_t half2 = 64 * rowB;
    const size_t halfB = 128 * rowB;

    const int tid = threadIdx.x, w = tid >> 6, lane = tid & 63;
    const int wm = w >> 2, wn = w & 3;

    const int srow = tid >> 3;
    const int scol_sw = ((tid & 7) * 16) ^ ((srow & 7) << 4);
    const int ldsW = w * 1024;

    const int lr = lane & 15;
    const int cks0 = ((lane >> 4) * 16) ^ ((lane & 7) << 4);
    const int cks1 = (64 + (lane >> 4) * 16) ^ ((lane & 7) << 4);
    const char* rdA0 = smem + (wm * 64 + lr) * 128 + cks0;
    const char* rdA1 = smem + (wm * 64 + lr) * 128 + cks1;
    const char* rdB0 = smem + (wn * 64 + lr) * 128 + cks0;
    const char* rdB1 = smem + (wn * 64 + lr) * 128 + cks1;

    const char* ga = (const char*)H + (size_t)tm * 128 * rowB + (size_t)srow * rowB + scol_sw;
    const char* gb = (const char*)W2T + (size_t)tn * 256 * rowB + (size_t)srow * rowB + scol_sw;

#define STG6(gAp, gBp, aOff, bOff) do { \
        g2lds16((gAp),                 smem + (aOff) + 0     + ldsW); \
        g2lds16((gAp) + half2,         smem + (aOff) + 8192  + ldsW); \
        g2lds16((gBp),                 smem + (bOff) + 0     + ldsW); \
        g2lds16((gBp) + half2,         smem + (bOff) + 8192  + ldsW); \
        g2lds16((gBp) + halfB,         smem + (bOff) + 16384 + ldsW); \
        g2lds16((gBp) + halfB + half2, smem + (bOff) + 24576 + ldsW); } while (0)

    f32x4 acc[4][4] = {};
    f32x4 oacc[4][4] = {};
    bf16x8 a0[4], a1[4], b0v[4], b1v[4];

    int aCur = 98304, aN1 = 114688, aN2 = 131072;
    int bCur = 0,     bN1 = 32768,  bN2 = 65536;

    STG6(ga, gb, aCur, bCur);
    STG6(ga + 128, gb + 128, aN1, bN1);
    WAITVM(6);
    BAR();

#pragma unroll
    for (int mf = 0; mf < 4; ++mf) a0[mf] = *(const bf16x8*)(rdA0 + aCur + mf * 2048);
#pragma unroll
    for (int nf = 0; nf < 4; ++nf) b0v[nf] = *(const bf16x8*)(rdB0 + bCur + nf * 2048);

    const int rbase = tm * 128 + wm * 64 + (lane >> 4) * 4;
    const int cbase = tn * 256 + wn * 64 + lr;

    for (int t = 0; t < 128; ++t) {
        const int t2 = t + 2;
        const bool moreS = (t2 < 128);
        const bool moreT = (t < 127);

        const char* gA2 = ga + (size_t)(t2 >> 4) * strAE + (t2 & 15) * 128;
        const char* gB2 = gb + (size_t)(t2 >> 4) * strBE + (t2 & 15) * 128;

        // ---- P0: prefetch ks1 frags (cur); stage (t+2) -> n2; MFMA ks0 (16)
#pragma unroll
        for (int mf = 0; mf < 4; ++mf) a1[mf] = *(const bf16x8*)(rdA1 + aCur + mf * 2048);
#pragma unroll
        for (int nf = 0; nf < 4; ++nf) b1v[nf] = *(const bf16x8*)(rdB1 + bCur + nf * 2048);
        if (moreS) STG6(gA2, gB2, aN2, bN2);
        __builtin_amdgcn_s_setprio(1);
#pragma unroll
        for (int mf = 0; mf < 4; ++mf)
#pragma unroll
            for (int nf = 0; nf < 4; ++nf)
                acc[mf][nf] = MFMA(a0[mf], b0v[nf], acc[mf][nf]);
        __builtin_amdgcn_s_setprio(0);

        // ---- P1: MFMA ks1 (16)
        __builtin_amdgcn_s_setprio(1);
#pragma unroll
        for (int mf = 0; mf < 4; ++mf)
#pragma unroll
            for (int nf = 0; nf < 4; ++nf)
                acc[mf][nf] = MFMA(a1[mf], b1v[nf], acc[mf][nf]);
        __builtin_amdgcn_s_setprio(0);

        // ---- boundary: t+1's loads landed (vmcnt leaves t+2's 6), all waves synced
        if (moreT) {
            if (moreS) { WAITVM(6); } else { WAITVM(0); }
            BAR();
#pragma unroll
            for (int mf = 0; mf < 4; ++mf) a0[mf] = *(const bf16x8*)(rdA0 + aN1 + mf * 2048);
#pragma unroll
            for (int nf = 0; nf < 4; ++nf) b0v[nf] = *(const bf16x8*)(rdB0 + bN1 + nf * 2048);
        }

        // ---- expert boundary: fold acc into gate-weighted out accumulator
        if ((t & 15) == 15) {
            const int e = t >> 4;
            float sc[4], tc[4];
#pragma unroll
            for (int nf = 0; nf < 4; ++nf) {
                sc[nf] = Sv[e * H2_ + cbase + nf * 16];
                tc[nf] = Tv[e * H2_ + cbase + nf * 16];
            }
#pragma unroll
            for (int mf = 0; mf < 4; ++mf) {
#pragma unroll
                for (int r = 0; r < 4; ++r) {
                    const int row = rbase + mf * 16 + r;
                    const float g = gate[(size_t)row * E_ + e];
#pragma unroll
                    for (int nf = 0; nf < 4; ++nf) {
                        float x = acc[mf][nf][r] * sc[nf] + tc[nf];
                        x = x > 0.f ? x : 0.f;
                        oacc[mf][nf][r] += g * x;
                    }
                }
            }
#pragma unroll
            for (int mf = 0; mf < 4; ++mf)
#pragma unroll
                for (int nf = 0; nf < 4; ++nf)
                    acc[mf][nf] = (f32x4){0.f, 0.f, 0.f, 0.f};
        }

        const int ta = aCur; aCur = aN1; aN1 = aN2; aN2 = ta;
        const int tb = bCur; bCur = bN1; bN1 = bN2; bN2 = tb;
    }

#pragma unroll
    for (int mf = 0; mf < 4; ++mf) {
#pragma unroll
        for (int r = 0; r < 4; ++r) {
            const int row = rbase + mf * 16 + r;
#pragma unroll
            for (int nf = 0; nf < 4; ++nf)
                outp[(size_t)row * H2_ + cbase + nf * 16] = oacc[mf][nf][r];
        }
    }
#undef STG6
}

// ---------------- launch ----------------

extern "C" void kernel_launch(void* const* d_in, const int* in_sizes, int n_in,
                              void* d_out, int out_size, void* d_ws, size_t ws_size,
                              hipStream_t stream) {
    (void)in_sizes; (void)n_in; (void)out_size; (void)ws_size;

    const float* input    = (const float*)d_in[0];
    const float* sideinfo = (const float*)d_in[1];
    const float* W1   = (const float*)d_in[2];
    const float* b1   = (const float*)d_in[3];
    const float* g1   = (const float*)d_in[4];
    const float* be1  = (const float*)d_in[5];
    const float* m1   = (const float*)d_in[6];
    const float* v1   = (const float*)d_in[7];
    const float* W2   = (const float*)d_in[8];
    const float* b2   = (const float*)d_in[9];
    const float* g2   = (const float*)d_in[10];
    const float* be2  = (const float*)d_in[11];
    const float* m2   = (const float*)d_in[12];
    const float* v2   = (const float*)d_in[13];
    const float* Wg   = (const float*)d_in[14];
    const float* bg   = (const float*)d_in[15];

    char* w = (char*)d_ws;
    size_t off = 0;
    auto carve = [&](size_t bytes) {
        void* p = w + off;
        off += (bytes + 255) & ~(size_t)255;
        return p;
    };
    ushort* Abf  = (ushort*)carve((size_t)B_ * D_ * 2);
    ushort* W1T  = (ushort*)carve((size_t)E_ * H1_ * D_ * 2);
    ushort* W2T  = (ushort*)carve((size_t)E_ * H2_ * H1_ * 2);
    ushort* hbuf = (ushort*)carve((size_t)E_ * B_ * H1_ * 2);
    float*  S1   = (float*)carve((size_t)E_ * H1_ * 4);
    float*  T1   = (float*)carve((size_t)E_ * H1_ * 4);
    float*  S2   = (float*)carve((size_t)E_ * H2_ * 4);
    float*  T2   = (float*)carve((size_t)E_ * H2_ * 4);
    float*  gatep = (float*)carve((size_t)B_ * E_ * 4);

    float* outp = (float*)d_out;

    hipFuncSetAttribute(reinterpret_cast<const void*>(&gemm8<1>),
                        hipFuncAttributeMaxDynamicSharedMemorySize, 163840);
    hipFuncSetAttribute(reinterpret_cast<const void*>(&gemm2e),
                        hipFuncAttributeMaxDynamicSharedMemorySize, 147456);

    cvt_bf16_kernel<<<4096, 256, 0, stream>>>(input, Abf, (long)B_ * D_);
    transpose_cvt_kernel<<<E_ * (D_ / 64) * (H1_ / 64), 256, 0, stream>>>(W1, W1T, D_, H1_);
    transpose_cvt_kernel<<<E_ * (H1_ / 64) * (H2_ / 64), 256, 0, stream>>>(W2, W2T, H1_, H2_);
    fold_bn_kernel<<<(E_ * H1_ + 255) / 256, 256, 0, stream>>>(g1, be1, m1, v1, b1, S1, T1, E_ * H1_);
    fold_bn_kernel<<<(E_ * H2_ + 255) / 256, 256, 0, stream>>>(g2, be2, m2, v2, b2, S2, T2, E_ * H2_);
    gate_kernel<<<B_ / 4, 256, 0, stream>>>(sideinfo, Wg, bg, gatep);

    // GEMM1: [B,D] x [D,H1] per expert -> h bf16 [E][B][H1]
    gemm8<1><<<E_ * (B_ / 256) * (H1_ / 256), 512, 163840, stream>>>(
        Abf, W1T, 0L, S1, T1, hbuf, nullptr, nullptr, B_, H1_, D_, H1_ / 256, B_ / 256);

    // GEMM2e: expert-loop, gate-weighted, writes out exactly once (no atomics)
    gemm2e<<<(B_ / 128) * (H2_ / 256), 512, 147456, stream>>>(
        hbuf, W2T, S2, T2, gatep, outp);
}